// Round 1
// baseline (11104.414 us; speedup 1.0000x reference)
//
#include <hip/hip_runtime.h>

#define H 128
#define EPS 1e-5f

// ---------------- degree histogram ----------------
__global__ void k_hist(const int* __restrict__ col, int E, int* __restrict__ deg){
  int i = blockIdx.x*blockDim.x+threadIdx.x;
  if(i<E) atomicAdd(&deg[col[i]],1);
}

// ---------------- 3-kernel exclusive scan of deg -> rowptr ----------------
__global__ void k_scan1(const int* __restrict__ deg, int N, int* __restrict__ bsum){
  __shared__ int s[512];
  int t=threadIdx.x; int i=blockIdx.x*512+t;
  s[t]=(i<N)?deg[i]:0; __syncthreads();
  for(int off=256;off>0;off>>=1){ if(t<off) s[t]+=s[t+off]; __syncthreads(); }
  if(t==0) bsum[blockIdx.x]=s[0];
}

__global__ void k_scan2(const int* __restrict__ bsum, int NB, int* __restrict__ boff){
  __shared__ int s[256];
  int t=threadIdx.x;
  int v=(t<NB)?bsum[t]:0;
  s[t]=v; __syncthreads();
  for(int off=1;off<256;off<<=1){ int u=(t>=off)?s[t-off]:0; __syncthreads(); s[t]+=u; __syncthreads(); }
  if(t<NB) boff[t]=s[t]-v;   // exclusive block offsets
}

__global__ void k_scan3(const int* __restrict__ deg, int N, int E, const int* __restrict__ boff,
                        int* __restrict__ rowptr, int* __restrict__ cursor, float* __restrict__ dnorm){
  __shared__ int s[512];
  int t=threadIdx.x; int i=blockIdx.x*512+t;
  int v=(i<N)?deg[i]:0;
  s[t]=v; __syncthreads();
  for(int off=1;off<512;off<<=1){ int u=(t>=off)?s[t-off]:0; __syncthreads(); s[t]+=u; __syncthreads(); }
  if(i<N){
    int ex=boff[blockIdx.x]+s[t]-v;     // exclusive prefix
    rowptr[i]=ex; cursor[i]=ex;
    dnorm[i]= (v>0) ? rsqrtf((float)v) : 0.f;  // nan_to_num: deg==0 -> coefficient 0
    if(i==N-1) rowptr[N]=E;
  }
}

// ---------------- CSR fill: pairs[pos] = (row, ew*dnorm[row]) ----------------
__global__ void k_fill(const int* __restrict__ row, const int* __restrict__ col,
                       const float* __restrict__ ew, int E, const float* __restrict__ dnorm,
                       int* __restrict__ cursor, float2* __restrict__ pairs){
  int e=blockIdx.x*blockDim.x+threadIdx.x;
  if(e<E){
    int r=row[e], d=col[e];
    int pos=atomicAdd(&cursor[d],1);
    pairs[pos]=make_float2(__int_as_float(r), ew[e]*dnorm[r]);
  }
}

// ---------------- SpMM: one 64-lane wave per destination, 2 cols/lane ----------------
__global__ __launch_bounds__(256) void k_spmm(const float2* __restrict__ pairs,
    const int* __restrict__ rowptr, const float* __restrict__ dnorm,
    const float* __restrict__ h, float* __restrict__ out, int N){
  int wid=(blockIdx.x*256+threadIdx.x)>>6;
  int lane=threadIdx.x&63;
  if(wid>=N) return;
  int beg=rowptr[wid], end=rowptr[wid+1];
  float ax=0.f, ay=0.f;
  for(int p=beg;p<end;++p){
    float2 pr=pairs[p];                       // wave-uniform 8B load (broadcast line)
    int r=__float_as_int(pr.x);
    float2 hv=*(const float2*)(h + ((size_t)r<<7) + (lane<<1));  // coalesced 512B row gather
    ax += pr.y*hv.x; ay += pr.y*hv.y;
  }
  float dn=dnorm[wid];
  *(float2*)(out + ((size_t)wid<<7) + (lane<<1)) = make_float2(ax*dn, ay*dn);
}

// ---------------- GEMM (N x 128 @ 128 x 128) + fused BN sum/sumsq ----------------
// 64 rows/block, 256 threads: thread = (cg = t&7 col-group, ra = t>>3 row) -> rows {ra, ra+32},
// cols {cg*4 + 32*jq + jr}. K staged in 4 chunks of 32. In-place safe (block reads only own rows
// into LDS before any store).
__global__ __launch_bounds__(256) void k_gemm_bn(const float* A, const float* __restrict__ W,
    const float* __restrict__ bias, float* Z, float* __restrict__ stats, int N){
  __shared__ float smem[8448];            // 33 KB: union of {sW 4096 + sA 2304} and {sPs 4224 + sPq 4224}
  float* sW = smem;
  float* sA = smem + 4096;                // [64][36] padded
  int t=threadIdx.x;
  int r0=blockIdx.x*64;
  int cg=t&7, ra=t>>3;
  float acc0[16], acc1[16];
  #pragma unroll
  for(int j=0;j<16;j++){ acc0[j]=0.f; acc1[j]=0.f; }

  for(int kb=0;kb<4;kb++){
    __syncthreads();
    #pragma unroll
    for(int i=t;i<1024;i+=256){           // W chunk: 32 x 128
      int kk=i>>5, c=(i&31)*4;
      *(float4*)&sW[kk*128+c] = *(const float4*)&W[(size_t)(kb*32+kk)*128 + c];
    }
    #pragma unroll
    for(int i=t;i<512;i+=256){            // A chunk: 64 x 32
      int r=i>>3, c=(i&7)*4;
      float4 v=make_float4(0.f,0.f,0.f,0.f);
      if(r0+r<N) v=*(const float4*)&A[(size_t)(r0+r)*128 + kb*32 + c];
      *(float4*)&sA[r*36+c]=v;
    }
    __syncthreads();
    for(int k=0;k<32;k++){
      float a0=sA[ra*36+k], a1=sA[(ra+32)*36+k];
      #pragma unroll
      for(int jq=0;jq<4;jq++){
        float4 w=*(const float4*)&sW[k*128 + cg*4 + 32*jq];
        acc0[jq*4+0]+=a0*w.x; acc0[jq*4+1]+=a0*w.y; acc0[jq*4+2]+=a0*w.z; acc0[jq*4+3]+=a0*w.w;
        acc1[jq*4+0]+=a1*w.x; acc1[jq*4+1]+=a1*w.y; acc1[jq*4+2]+=a1*w.z; acc1[jq*4+3]+=a1*w.w;
      }
    }
  }

  __syncthreads();                         // smem reuse as stats partials
  float* sPs = smem;                       // [32][132]
  float* sPq = smem + 4224;
  int row0=r0+ra, row1=r0+ra+32;
  #pragma unroll
  for(int jq=0;jq<4;jq++){
    int c0=cg*4+32*jq;
    float4 b4=*(const float4*)&bias[c0];
    float4 z0=make_float4(acc0[jq*4]+b4.x, acc0[jq*4+1]+b4.y, acc0[jq*4+2]+b4.z, acc0[jq*4+3]+b4.w);
    float4 z1=make_float4(acc1[jq*4]+b4.x, acc1[jq*4+1]+b4.y, acc1[jq*4+2]+b4.z, acc1[jq*4+3]+b4.w);
    float4 ss=make_float4(0.f,0.f,0.f,0.f), sq=make_float4(0.f,0.f,0.f,0.f);
    if(row0<N){
      *(float4*)&Z[(size_t)row0*128+c0]=z0;
      ss.x+=z0.x; ss.y+=z0.y; ss.z+=z0.z; ss.w+=z0.w;
      sq.x+=z0.x*z0.x; sq.y+=z0.y*z0.y; sq.z+=z0.z*z0.z; sq.w+=z0.w*z0.w;
    }
    if(row1<N){
      *(float4*)&Z[(size_t)row1*128+c0]=z1;
      ss.x+=z1.x; ss.y+=z1.y; ss.z+=z1.z; ss.w+=z1.w;
      sq.x+=z1.x*z1.x; sq.y+=z1.y*z1.y; sq.z+=z1.z*z1.z; sq.w+=z1.w*z1.w;
    }
    *(float4*)&sPs[ra*132+c0]=ss;
    *(float4*)&sPq[ra*132+c0]=sq;
  }
  __syncthreads();
  if(t<128){
    float s=0.f,q=0.f;
    #pragma unroll 8
    for(int g=0;g<32;g++){ s+=sPs[g*132+t]; q+=sPq[g*132+t]; }
    atomicAdd(&stats[t],s); atomicAdd(&stats[128+t],q);
  }
}

// ---------------- finalize BN: per-channel scale/shift ----------------
__global__ void k_bnfin(const float* __restrict__ stats, const float* __restrict__ gamma,
                        const float* __restrict__ beta, float* __restrict__ mi, float invN){
  int c=threadIdx.x;                       // 128 threads
  float mean=stats[c]*invN;
  float var=stats[128+c]*invN - mean*mean;
  float inv=rsqrtf(var+EPS);
  float sc=inv*gamma[c];
  mi[c]=sc; mi[128+c]=beta[c]-mean*sc;
}

// ---------------- apply BN + ReLU (+ residual) ----------------
__global__ __launch_bounds__(256) void k_apply(const float* __restrict__ Z, const float* __restrict__ mi,
    const float* __restrict__ res, float* __restrict__ out, int n4){
  int i=blockIdx.x*256+threadIdx.x;
  if(i>=n4) return;
  int c=(i&31)*4;
  float4 z=((const float4*)Z)[i];
  float4 sc=*(const float4*)&mi[c];
  float4 sh=*(const float4*)&mi[128+c];
  float4 o;
  o.x=fmaxf(fmaf(z.x,sc.x,sh.x),0.f);
  o.y=fmaxf(fmaf(z.y,sc.y,sh.y),0.f);
  o.z=fmaxf(fmaf(z.z,sc.z,sh.z),0.f);
  o.w=fmaxf(fmaf(z.w,sc.w,sh.w),0.f);
  if(res){
    float4 r=((const float4*)res)[i];
    o.x+=r.x; o.y+=r.y; o.z+=r.z; o.w+=r.w;
  }
  ((float4*)out)[i]=o;
}

extern "C" void kernel_launch(void* const* d_in, const int* in_sizes, int n_in,
                              void* d_out, int out_size, void* d_ws, size_t ws_size,
                              hipStream_t stream){
  const float* x      = (const float*)d_in[0];
  const int*   ei     = (const int*)  d_in[1];
  const float* ew     = (const float*)d_in[2];
  const float* fc_w   = (const float*)d_in[3];
  const float* fc_b   = (const float*)d_in[4];
  const float* conv_w = (const float*)d_in[5];
  const float* conv_b = (const float*)d_in[6];
  const float* gamma  = (const float*)d_in[7];
  const float* beta   = (const float*)d_in[8];
  float* out = (float*)d_out;

  int N = in_sizes[0]/H;
  int E = in_sizes[2];
  const int* row = ei;
  const int* col = ei + E;

  // workspace layout (~66 MB)
  size_t NH = (size_t)N*H;
  float*  zbuf   = (float*)d_ws;               // N*H
  float2* pairs  = (float2*)(zbuf + NH);       // E
  float*  stats  = (float*)(pairs + E);        // 3*256 (sum, sumsq per stage)
  float*  mi     = stats + 768;                // 3*256 (scale, shift per stage)
  int*    deg    = (int*)(mi + 768);           // N
  float*  dnorm  = (float*)(deg + N);          // N
  int*    rowptr = (int*)(dnorm + N);          // N+1
  int*    cursor = rowptr + (N+1);             // N
  int*    bsum   = cursor + N;                 // 256
  int*    boff   = bsum + 256;                 // 256

  hipMemsetAsync(deg, 0, sizeof(int)*(size_t)N, stream);
  hipMemsetAsync(stats, 0, sizeof(float)*768, stream);

  int gE = (E+255)/256;
  k_hist<<<gE,256,0,stream>>>(col,E,deg);
  int NB=(N+511)/512;
  k_scan1<<<NB,512,0,stream>>>(deg,N,bsum);
  k_scan2<<<1,256,0,stream>>>(bsum,NB,boff);
  k_scan3<<<NB,512,0,stream>>>(deg,N,E,boff,rowptr,cursor,dnorm);
  k_fill<<<gE,256,0,stream>>>(row,col,ew,E,dnorm,cursor,pairs);

  int GB=(N+63)/64;
  int gApply=((N*32)+255)/256;
  int gSpmm=(N+3)/4;
  float invN=1.f/(float)N;

  // stage 0: h = relu(bn(x @ fc_w + fc_b))
  k_gemm_bn<<<GB,256,0,stream>>>(x, fc_w, fc_b, zbuf, stats, N);
  k_bnfin<<<1,128,0,stream>>>(stats, gamma, beta, mi, invN);
  k_apply<<<gApply,256,0,stream>>>(zbuf, mi, nullptr, out, N*32);

  // layers: z = relu(bn(agg(h) @ Wl + bl)); h = z + h
  for(int l=0;l<2;l++){
    k_spmm<<<gSpmm,256,0,stream>>>(pairs,rowptr,dnorm,out,zbuf,N);
    k_gemm_bn<<<GB,256,0,stream>>>(zbuf, conv_w + (size_t)l*H*H, conv_b + (size_t)l*H,
                                   zbuf, stats+256*(l+1), N);
    k_bnfin<<<1,128,0,stream>>>(stats+256*(l+1), gamma+H*(l+1), beta+H*(l+1), mi+256*(l+1), invN);
    k_apply<<<gApply,256,0,stream>>>(zbuf, mi+256*(l+1), out, out, N*32);
  }
}

// Round 2
// 963.367 us; speedup vs baseline: 11.5267x; 11.5267x over previous
//
#include <hip/hip_runtime.h>

#define H 128
#define EPS 1e-5f

// ---------------- degree histogram ----------------
__global__ void k_hist(const int* __restrict__ col, int E, int* __restrict__ deg){
  int i = blockIdx.x*blockDim.x+threadIdx.x;
  if(i<E) atomicAdd(&deg[col[i]],1);
}

// ---------------- 3-kernel exclusive scan of deg -> rowptr ----------------
__global__ void k_scan1(const int* __restrict__ deg, int N, int* __restrict__ bsum){
  __shared__ int s[512];
  int t=threadIdx.x; int i=blockIdx.x*512+t;
  s[t]=(i<N)?deg[i]:0; __syncthreads();
  for(int off=256;off>0;off>>=1){ if(t<off) s[t]+=s[t+off]; __syncthreads(); }
  if(t==0) bsum[blockIdx.x]=s[0];
}

__global__ void k_scan2(const int* __restrict__ bsum, int NB, int* __restrict__ boff){
  __shared__ int s[256];
  int t=threadIdx.x;
  int v=(t<NB)?bsum[t]:0;
  s[t]=v; __syncthreads();
  for(int off=1;off<256;off<<=1){ int u=(t>=off)?s[t-off]:0; __syncthreads(); s[t]+=u; __syncthreads(); }
  if(t<NB) boff[t]=s[t]-v;   // exclusive block offsets
}

__global__ void k_scan3(const int* __restrict__ deg, int N, int E, const int* __restrict__ boff,
                        int* __restrict__ rowptr, int* __restrict__ cursor, float* __restrict__ dnorm){
  __shared__ int s[512];
  int t=threadIdx.x; int i=blockIdx.x*512+t;
  int v=(i<N)?deg[i]:0;
  s[t]=v; __syncthreads();
  for(int off=1;off<512;off<<=1){ int u=(t>=off)?s[t-off]:0; __syncthreads(); s[t]+=u; __syncthreads(); }
  if(i<N){
    int ex=boff[blockIdx.x]+s[t]-v;     // exclusive prefix
    rowptr[i]=ex; cursor[i]=ex;
    dnorm[i]= (v>0) ? rsqrtf((float)v) : 0.f;  // nan_to_num: deg==0 -> coefficient 0
    if(i==N-1) rowptr[N]=E;
  }
}

// ---------------- CSR fill: pairs[pos] = (row, ew*dnorm[row]) ----------------
__global__ void k_fill(const int* __restrict__ row, const int* __restrict__ col,
                       const float* __restrict__ ew, int E, const float* __restrict__ dnorm,
                       int* __restrict__ cursor, float2* __restrict__ pairs){
  int e=blockIdx.x*blockDim.x+threadIdx.x;
  if(e<E){
    int r=row[e], d=col[e];
    int pos=atomicAdd(&cursor[d],1);
    pairs[pos]=make_float2(__int_as_float(r), ew[e]*dnorm[r]);
  }
}

// ---------------- SpMM: one 64-lane wave per destination, 2 cols/lane ----------------
__global__ __launch_bounds__(256) void k_spmm(const float2* __restrict__ pairs,
    const int* __restrict__ rowptr, const float* __restrict__ dnorm,
    const float* __restrict__ h, float* __restrict__ out, int N){
  int wid=(blockIdx.x*256+threadIdx.x)>>6;
  int lane=threadIdx.x&63;
  if(wid>=N) return;
  int beg=rowptr[wid], end=rowptr[wid+1];
  float ax=0.f, ay=0.f;
  for(int p=beg;p<end;++p){
    float2 pr=pairs[p];                       // wave-uniform 8B load (broadcast line)
    int r=__float_as_int(pr.x);
    float2 hv=*(const float2*)(h + ((size_t)r<<7) + (lane<<1));  // coalesced 512B row gather
    ax += pr.y*hv.x; ay += pr.y*hv.y;
  }
  float dn=dnorm[wid];
  *(float2*)(out + ((size_t)wid<<7) + (lane<<1)) = make_float2(ax*dn, ay*dn);
}

// ---------------- GEMM (N x 128 @ 128 x 128) + fused BN sum/sumsq ----------------
// v2: spill-proof. 32 rows x 128 cols per block, 256 threads, 4x4 register tile
// (16 accs). K chunked 2x64. A staged TRANSPOSED (sAT[k][r], pitch 36) so the
// inner loop is 2x ds_read_b128 + 16 FMA per k. __launch_bounds__(256,4) caps
// VGPR at 128 (v1's 32-acc layout spilled at 256 VGPR -> 7 GB scratch traffic).
// In-place safe: Z stores only in epilogue, after all A reads.
__global__ __launch_bounds__(256,4) void k_gemm_bn(const float* A, const float* __restrict__ W,
    const float* __restrict__ bias, float* Z, float* __restrict__ stats, int N){
  __shared__ float smem[10496];           // sW 8192 (32KB) + sAT 64*36=2304 (9KB)
  float* sW  = smem;                      // [64][128] chunk of W
  float* sAT = smem + 8192;               // [64][36]: sAT[k][r], padded pitch
  int t=threadIdx.x;
  int r0=blockIdx.x*32;
  int ct=t&31, rt=t>>5;                   // ct: 32 col-groups of 4; rt: 8 row-groups of 4
  float acc[4][4];
  #pragma unroll
  for(int i=0;i<4;i++)
    #pragma unroll
    for(int j=0;j<4;j++) acc[i][j]=0.f;

  for(int kb=0;kb<2;kb++){
    __syncthreads();
    #pragma unroll
    for(int i=t;i<2048;i+=256){           // W chunk: 64 x 128
      int kk=i>>5, c=(i&31)*4;
      *(float4*)&sW[kk*128+c] = *(const float4*)&W[(size_t)(kb*64+kk)*128 + c];
    }
    #pragma unroll
    for(int i=t;i<512;i+=256){            // A chunk: 32 rows x 64 k, transposed scatter
      int r=i>>4, k4=(i&15)*4;
      float4 v=make_float4(0.f,0.f,0.f,0.f);
      if(r0+r<N) v=*(const float4*)&A[(size_t)(r0+r)*128 + kb*64 + k4];
      sAT[(k4+0)*36+r]=v.x; sAT[(k4+1)*36+r]=v.y; sAT[(k4+2)*36+r]=v.z; sAT[(k4+3)*36+r]=v.w;
    }
    __syncthreads();
    for(int k=0;k<64;k++){
      float4 a4=*(const float4*)&sAT[k*36 + rt*4];
      float4 w4=*(const float4*)&sW[k*128 + ct*4];
      acc[0][0]+=a4.x*w4.x; acc[0][1]+=a4.x*w4.y; acc[0][2]+=a4.x*w4.z; acc[0][3]+=a4.x*w4.w;
      acc[1][0]+=a4.y*w4.x; acc[1][1]+=a4.y*w4.y; acc[1][2]+=a4.y*w4.z; acc[1][3]+=a4.y*w4.w;
      acc[2][0]+=a4.z*w4.x; acc[2][1]+=a4.z*w4.y; acc[2][2]+=a4.z*w4.z; acc[2][3]+=a4.z*w4.w;
      acc[3][0]+=a4.w*w4.x; acc[3][1]+=a4.w*w4.y; acc[3][2]+=a4.w*w4.z; acc[3][3]+=a4.w*w4.w;
    }
  }

  __syncthreads();                         // reuse smem for stats partials
  float* sSum = smem;                      // [8][132]
  float* sSq  = smem + 1056;               // [8][132]
  int c0=ct*4;
  float4 b4=*(const float4*)&bias[c0];
  float4 ps=make_float4(0.f,0.f,0.f,0.f), pq=make_float4(0.f,0.f,0.f,0.f);
  #pragma unroll
  for(int i=0;i<4;i++){
    int r=r0+rt*4+i;
    float4 z=make_float4(acc[i][0]+b4.x, acc[i][1]+b4.y, acc[i][2]+b4.z, acc[i][3]+b4.w);
    if(r<N){
      *(float4*)&Z[(size_t)r*128+c0]=z;
      ps.x+=z.x; ps.y+=z.y; ps.z+=z.z; ps.w+=z.w;
      pq.x+=z.x*z.x; pq.y+=z.y*z.y; pq.z+=z.z*z.z; pq.w+=z.w*z.w;
    }
  }
  *(float4*)&sSum[rt*132+c0]=ps;
  *(float4*)&sSq [rt*132+c0]=pq;
  __syncthreads();
  if(t<128){
    float s=0.f,q=0.f;
    #pragma unroll
    for(int g=0;g<8;g++){ s+=sSum[g*132+t]; q+=sSq[g*132+t]; }
    atomicAdd(&stats[t],s); atomicAdd(&stats[128+t],q);
  }
}

// ---------------- finalize BN: per-channel scale/shift ----------------
__global__ void k_bnfin(const float* __restrict__ stats, const float* __restrict__ gamma,
                        const float* __restrict__ beta, float* __restrict__ mi, float invN){
  int c=threadIdx.x;                       // 128 threads
  float mean=stats[c]*invN;
  float var=stats[128+c]*invN - mean*mean;
  float inv=rsqrtf(var+EPS);
  float sc=inv*gamma[c];
  mi[c]=sc; mi[128+c]=beta[c]-mean*sc;
}

// ---------------- apply BN + ReLU (+ residual) ----------------
__global__ __launch_bounds__(256) void k_apply(const float* __restrict__ Z, const float* __restrict__ mi,
    const float* __restrict__ res, float* __restrict__ out, int n4){
  int i=blockIdx.x*256+threadIdx.x;
  if(i>=n4) return;
  int c=(i&31)*4;
  float4 z=((const float4*)Z)[i];
  float4 sc=*(const float4*)&mi[c];
  float4 sh=*(const float4*)&mi[128+c];
  float4 o;
  o.x=fmaxf(fmaf(z.x,sc.x,sh.x),0.f);
  o.y=fmaxf(fmaf(z.y,sc.y,sh.y),0.f);
  o.z=fmaxf(fmaf(z.z,sc.z,sh.z),0.f);
  o.w=fmaxf(fmaf(z.w,sc.w,sh.w),0.f);
  if(res){
    float4 r=((const float4*)res)[i];
    o.x+=r.x; o.y+=r.y; o.z+=r.z; o.w+=r.w;
  }
  ((float4*)out)[i]=o;
}

extern "C" void kernel_launch(void* const* d_in, const int* in_sizes, int n_in,
                              void* d_out, int out_size, void* d_ws, size_t ws_size,
                              hipStream_t stream){
  const float* x      = (const float*)d_in[0];
  const int*   ei     = (const int*)  d_in[1];
  const float* ew     = (const float*)d_in[2];
  const float* fc_w   = (const float*)d_in[3];
  const float* fc_b   = (const float*)d_in[4];
  const float* conv_w = (const float*)d_in[5];
  const float* conv_b = (const float*)d_in[6];
  const float* gamma  = (const float*)d_in[7];
  const float* beta   = (const float*)d_in[8];
  float* out = (float*)d_out;

  int N = in_sizes[0]/H;
  int E = in_sizes[2];
  const int* row = ei;
  const int* col = ei + E;

  // workspace layout (~66 MB)
  size_t NH = (size_t)N*H;
  float*  zbuf   = (float*)d_ws;               // N*H
  float2* pairs  = (float2*)(zbuf + NH);       // E
  float*  stats  = (float*)(pairs + E);        // 3*256 (sum, sumsq per stage)
  float*  mi     = stats + 768;                // 3*256 (scale, shift per stage)
  int*    deg    = (int*)(mi + 768);           // N
  float*  dnorm  = (float*)(deg + N);          // N
  int*    rowptr = (int*)(dnorm + N);          // N+1
  int*    cursor = rowptr + (N+1);             // N
  int*    bsum   = cursor + N;                 // 256
  int*    boff   = bsum + 256;                 // 256

  hipMemsetAsync(deg, 0, sizeof(int)*(size_t)N, stream);
  hipMemsetAsync(stats, 0, sizeof(float)*768, stream);

  int gE = (E+255)/256;
  k_hist<<<gE,256,0,stream>>>(col,E,deg);
  int NB=(N+511)/512;
  k_scan1<<<NB,512,0,stream>>>(deg,N,bsum);
  k_scan2<<<1,256,0,stream>>>(bsum,NB,boff);
  k_scan3<<<NB,512,0,stream>>>(deg,N,E,boff,rowptr,cursor,dnorm);
  k_fill<<<gE,256,0,stream>>>(row,col,ew,E,dnorm,cursor,pairs);

  int GB=(N+31)/32;
  int gApply=((N*32)+255)/256;
  int gSpmm=(N+3)/4;
  float invN=1.f/(float)N;

  // stage 0: h = relu(bn(x @ fc_w + fc_b))
  k_gemm_bn<<<GB,256,0,stream>>>(x, fc_w, fc_b, zbuf, stats, N);
  k_bnfin<<<1,128,0,stream>>>(stats, gamma, beta, mi, invN);
  k_apply<<<gApply,256,0,stream>>>(zbuf, mi, nullptr, out, N*32);

  // layers: z = relu(bn(agg(h) @ Wl + bl)); h = z + h
  for(int l=0;l<2;l++){
    k_spmm<<<gSpmm,256,0,stream>>>(pairs,rowptr,dnorm,out,zbuf,N);
    k_gemm_bn<<<GB,256,0,stream>>>(zbuf, conv_w + (size_t)l*H*H, conv_b + (size_t)l*H,
                                   zbuf, stats+256*(l+1), N);
    k_bnfin<<<1,128,0,stream>>>(stats+256*(l+1), gamma+H*(l+1), beta+H*(l+1), mi+256*(l+1), invN);
    k_apply<<<gApply,256,0,stream>>>(zbuf, mi+256*(l+1), out, out, N*32);
  }
}

// Round 3
// 805.412 us; speedup vs baseline: 13.7872x; 1.1961x over previous
//
#include <hip/hip_runtime.h>

#define H 128
#define EPS 1e-5f

// ---------------- degree histogram ----------------
__global__ void k_hist(const int* __restrict__ col, int E, int* __restrict__ deg){
  int i = blockIdx.x*blockDim.x+threadIdx.x;
  if(i<E) atomicAdd(&deg[col[i]],1);
}

// ---------------- 3-kernel exclusive scan of deg -> rowptr ----------------
__global__ void k_scan1(const int* __restrict__ deg, int N, int* __restrict__ bsum){
  __shared__ int s[512];
  int t=threadIdx.x; int i=blockIdx.x*512+t;
  s[t]=(i<N)?deg[i]:0; __syncthreads();
  for(int off=256;off>0;off>>=1){ if(t<off) s[t]+=s[t+off]; __syncthreads(); }
  if(t==0) bsum[blockIdx.x]=s[0];
}

__global__ void k_scan2(const int* __restrict__ bsum, int NB, int* __restrict__ boff){
  __shared__ int s[256];
  int t=threadIdx.x;
  int v=(t<NB)?bsum[t]:0;
  s[t]=v; __syncthreads();
  for(int off=1;off<256;off<<=1){ int u=(t>=off)?s[t-off]:0; __syncthreads(); s[t]+=u; __syncthreads(); }
  if(t<NB) boff[t]=s[t]-v;   // exclusive block offsets
}

__global__ void k_scan3(const int* __restrict__ deg, int N, int E, const int* __restrict__ boff,
                        int* __restrict__ rowptr, int* __restrict__ cursor, float* __restrict__ dnorm){
  __shared__ int s[512];
  int t=threadIdx.x; int i=blockIdx.x*512+t;
  int v=(i<N)?deg[i]:0;
  s[t]=v; __syncthreads();
  for(int off=1;off<512;off<<=1){ int u=(t>=off)?s[t-off]:0; __syncthreads(); s[t]+=u; __syncthreads(); }
  if(i<N){
    int ex=boff[blockIdx.x]+s[t]-v;     // exclusive prefix
    rowptr[i]=ex; cursor[i]=ex;
    dnorm[i]= (v>0) ? rsqrtf((float)v) : 0.f;  // nan_to_num: deg==0 -> coefficient 0
    if(i==N-1) rowptr[N]=E;
  }
}

// ---------------- CSR fill: pairs[pos] = (row, ew*dnorm[row]) ----------------
__global__ void k_fill(const int* __restrict__ row, const int* __restrict__ col,
                       const float* __restrict__ ew, int E, const float* __restrict__ dnorm,
                       int* __restrict__ cursor, float2* __restrict__ pairs){
  int e=blockIdx.x*blockDim.x+threadIdx.x;
  if(e<E){
    int r=row[e], d=col[e];
    int pos=atomicAdd(&cursor[d],1);
    pairs[pos]=make_float2(__int_as_float(r), ew[e]*dnorm[r]);
  }
}

// ---------------- SpMM fp32 fallback (used only if ws too small for bf16 h) ----------------
__global__ __launch_bounds__(256) void k_spmm(const float2* __restrict__ pairs,
    const int* __restrict__ rowptr, const float* __restrict__ dnorm,
    const float* __restrict__ h, float* __restrict__ out, int N){
  int wid=(blockIdx.x*256+threadIdx.x)>>6;
  int lane=threadIdx.x&63;
  if(wid>=N) return;
  int beg=rowptr[wid], end=rowptr[wid+1];
  float ax=0.f, ay=0.f;
  for(int p=beg;p<end;++p){
    float2 pr=pairs[p];
    int r=__float_as_int(pr.x);
    float2 hv=*(const float2*)(h + ((size_t)r<<7) + (lane<<1));
    ax += pr.y*hv.x; ay += pr.y*hv.y;
  }
  float dn=dnorm[wid];
  *(float2*)(out + ((size_t)wid<<7) + (lane<<1)) = make_float2(ax*dn, ay*dn);
}

// ---------------- SpMM bf16: wave/dest, 2 cols/lane (1 dword gather), unroll x4 ----------------
// Latency fix vs v2: 4 pair loads then 4 independent row gathers in flight before any
// FMA (v2 serialized pairs->gather->fma per edge). bf16 h halves gather bytes; h_bf
// (25.6 MB) is L3-resident.
__global__ __launch_bounds__(256) void k_spmm_bf(const float2* __restrict__ pairs,
    const int* __restrict__ rowptr, const float* __restrict__ dnorm,
    const unsigned short* __restrict__ hb, float* __restrict__ out, int N){
  int wid=(blockIdx.x*256+threadIdx.x)>>6;
  int lane=threadIdx.x&63;
  if(wid>=N) return;
  int beg=rowptr[wid], end=rowptr[wid+1];
  float ax=0.f, ay=0.f;
  int p=beg;
  for(; p+4<=end; p+=4){
    float2 pr0=pairs[p+0], pr1=pairs[p+1], pr2=pairs[p+2], pr3=pairs[p+3];
    unsigned int u0=*(const unsigned int*)(hb + (((size_t)__float_as_int(pr0.x))<<7) + (lane<<1));
    unsigned int u1=*(const unsigned int*)(hb + (((size_t)__float_as_int(pr1.x))<<7) + (lane<<1));
    unsigned int u2=*(const unsigned int*)(hb + (((size_t)__float_as_int(pr2.x))<<7) + (lane<<1));
    unsigned int u3=*(const unsigned int*)(hb + (((size_t)__float_as_int(pr3.x))<<7) + (lane<<1));
    ax=fmaf(pr0.y,__uint_as_float(u0<<16),ax); ay=fmaf(pr0.y,__uint_as_float(u0&0xFFFF0000u),ay);
    ax=fmaf(pr1.y,__uint_as_float(u1<<16),ax); ay=fmaf(pr1.y,__uint_as_float(u1&0xFFFF0000u),ay);
    ax=fmaf(pr2.y,__uint_as_float(u2<<16),ax); ay=fmaf(pr2.y,__uint_as_float(u2&0xFFFF0000u),ay);
    ax=fmaf(pr3.y,__uint_as_float(u3<<16),ax); ay=fmaf(pr3.y,__uint_as_float(u3&0xFFFF0000u),ay);
  }
  for(; p<end; ++p){
    float2 pr=pairs[p];
    unsigned int u=*(const unsigned int*)(hb + (((size_t)__float_as_int(pr.x))<<7) + (lane<<1));
    ax=fmaf(pr.y,__uint_as_float(u<<16),ax); ay=fmaf(pr.y,__uint_as_float(u&0xFFFF0000u),ay);
  }
  float dn=dnorm[wid];
  *(float2*)(out + ((size_t)wid<<7) + (lane<<1)) = make_float2(ax*dn, ay*dn);
}

// ---------------- GEMM (N x 128 @ 128 x 128) + fused BN sum/sumsq ----------------
// 32 rows x 128 cols per block, 256 threads, 4x4 register tile. K chunked 2x64.
// A staged TRANSPOSED (sAT[k][r], pitch 36). __launch_bounds__(256,4) caps VGPR at 128
// (v1's 32-acc layout spilled at 256 VGPR -> 7 GB scratch traffic). In-place safe.
__global__ __launch_bounds__(256,4) void k_gemm_bn(const float* A, const float* __restrict__ W,
    const float* __restrict__ bias, float* Z, float* __restrict__ stats, int N){
  __shared__ float smem[10496];           // sW 8192 + sAT 64*36=2304
  float* sW  = smem;                      // [64][128] chunk of W
  float* sAT = smem + 8192;               // [64][36]: sAT[k][r], padded pitch
  int t=threadIdx.x;
  int r0=blockIdx.x*32;
  int ct=t&31, rt=t>>5;
  float acc[4][4];
  #pragma unroll
  for(int i=0;i<4;i++)
    #pragma unroll
    for(int j=0;j<4;j++) acc[i][j]=0.f;

  for(int kb=0;kb<2;kb++){
    __syncthreads();
    #pragma unroll
    for(int i=t;i<2048;i+=256){           // W chunk: 64 x 128
      int kk=i>>5, c=(i&31)*4;
      *(float4*)&sW[kk*128+c] = *(const float4*)&W[(size_t)(kb*64+kk)*128 + c];
    }
    #pragma unroll
    for(int i=t;i<512;i+=256){            // A chunk: 32 rows x 64 k, transposed scatter
      int r=i>>4, k4=(i&15)*4;
      float4 v=make_float4(0.f,0.f,0.f,0.f);
      if(r0+r<N) v=*(const float4*)&A[(size_t)(r0+r)*128 + kb*64 + k4];
      sAT[(k4+0)*36+r]=v.x; sAT[(k4+1)*36+r]=v.y; sAT[(k4+2)*36+r]=v.z; sAT[(k4+3)*36+r]=v.w;
    }
    __syncthreads();
    for(int k=0;k<64;k++){
      float4 a4=*(const float4*)&sAT[k*36 + rt*4];
      float4 w4=*(const float4*)&sW[k*128 + ct*4];
      acc[0][0]+=a4.x*w4.x; acc[0][1]+=a4.x*w4.y; acc[0][2]+=a4.x*w4.z; acc[0][3]+=a4.x*w4.w;
      acc[1][0]+=a4.y*w4.x; acc[1][1]+=a4.y*w4.y; acc[1][2]+=a4.y*w4.z; acc[1][3]+=a4.y*w4.w;
      acc[2][0]+=a4.z*w4.x; acc[2][1]+=a4.z*w4.y; acc[2][2]+=a4.z*w4.z; acc[2][3]+=a4.z*w4.w;
      acc[3][0]+=a4.w*w4.x; acc[3][1]+=a4.w*w4.y; acc[3][2]+=a4.w*w4.z; acc[3][3]+=a4.w*w4.w;
    }
  }

  __syncthreads();                         // reuse smem for stats partials
  float* sSum = smem;                      // [8][132]
  float* sSq  = smem + 1056;               // [8][132]
  int c0=ct*4;
  float4 b4=*(const float4*)&bias[c0];
  float4 ps=make_float4(0.f,0.f,0.f,0.f), pq=make_float4(0.f,0.f,0.f,0.f);
  #pragma unroll
  for(int i=0;i<4;i++){
    int r=r0+rt*4+i;
    float4 z=make_float4(acc[i][0]+b4.x, acc[i][1]+b4.y, acc[i][2]+b4.z, acc[i][3]+b4.w);
    if(r<N){
      *(float4*)&Z[(size_t)r*128+c0]=z;
      ps.x+=z.x; ps.y+=z.y; ps.z+=z.z; ps.w+=z.w;
      pq.x+=z.x*z.x; pq.y+=z.y*z.y; pq.z+=z.z*z.z; pq.w+=z.w*z.w;
    }
  }
  *(float4*)&sSum[rt*132+c0]=ps;
  *(float4*)&sSq [rt*132+c0]=pq;
  __syncthreads();
  if(t<128){
    float s=0.f,q=0.f;
    #pragma unroll
    for(int g=0;g<8;g++){ s+=sSum[g*132+t]; q+=sSq[g*132+t]; }
    atomicAdd(&stats[t],s); atomicAdd(&stats[128+t],q);
  }
}

// ---------------- finalize BN: per-channel scale/shift ----------------
__global__ void k_bnfin(const float* __restrict__ stats, const float* __restrict__ gamma,
                        const float* __restrict__ beta, float* __restrict__ mi, float invN){
  int c=threadIdx.x;                       // 128 threads
  float mean=stats[c]*invN;
  float var=stats[128+c]*invN - mean*mean;
  float inv=rsqrtf(var+EPS);
  float sc=inv*gamma[c];
  mi[c]=sc; mi[128+c]=beta[c]-mean*sc;
}

// ---------------- apply BN + ReLU (+ residual) (+ bf16 shadow write) ----------------
__device__ inline unsigned int pack_bf16(float a, float b){
  unsigned int ua=__float_as_uint(a), ub=__float_as_uint(b);
  ua = (ua + 0x7FFFu + ((ua>>16)&1u)) >> 16;
  ub = (ub + 0x7FFFu + ((ub>>16)&1u)) & 0xFFFF0000u;
  return ua | ub;
}

__global__ __launch_bounds__(256) void k_apply(const float* __restrict__ Z, const float* __restrict__ mi,
    const float* __restrict__ res, float* __restrict__ out, unsigned short* __restrict__ hb, int n4){
  int i=blockIdx.x*256+threadIdx.x;
  if(i>=n4) return;
  int c=(i&31)*4;
  float4 z=((const float4*)Z)[i];
  float4 sc=*(const float4*)&mi[c];
  float4 sh=*(const float4*)&mi[128+c];
  float4 o;
  o.x=fmaxf(fmaf(z.x,sc.x,sh.x),0.f);
  o.y=fmaxf(fmaf(z.y,sc.y,sh.y),0.f);
  o.z=fmaxf(fmaf(z.z,sc.z,sh.z),0.f);
  o.w=fmaxf(fmaf(z.w,sc.w,sh.w),0.f);
  if(res){
    float4 r=((const float4*)res)[i];
    o.x+=r.x; o.y+=r.y; o.z+=r.z; o.w+=r.w;
  }
  ((float4*)out)[i]=o;
  if(hb){
    uint2 pk; pk.x=pack_bf16(o.x,o.y); pk.y=pack_bf16(o.z,o.w);
    ((uint2*)hb)[i]=pk;
  }
}

extern "C" void kernel_launch(void* const* d_in, const int* in_sizes, int n_in,
                              void* d_out, int out_size, void* d_ws, size_t ws_size,
                              hipStream_t stream){
  const float* x      = (const float*)d_in[0];
  const int*   ei     = (const int*)  d_in[1];
  const float* ew     = (const float*)d_in[2];
  const float* fc_w   = (const float*)d_in[3];
  const float* fc_b   = (const float*)d_in[4];
  const float* conv_w = (const float*)d_in[5];
  const float* conv_b = (const float*)d_in[6];
  const float* gamma  = (const float*)d_in[7];
  const float* beta   = (const float*)d_in[8];
  float* out = (float*)d_out;

  int N = in_sizes[0]/H;
  int E = in_sizes[2];
  const int* row = ei;
  const int* col = ei + E;

  // workspace layout
  size_t NH = (size_t)N*H;
  float*  zbuf   = (float*)d_ws;               // N*H fp32
  float2* pairs  = (float2*)(zbuf + NH);       // E
  float*  stats  = (float*)(pairs + E);        // 3*256
  float*  mi     = stats + 768;                // 3*256
  int*    deg    = (int*)(mi + 768);           // N
  float*  dnorm  = (float*)(deg + N);          // N
  int*    rowptr = (int*)(dnorm + N);          // N+1
  int*    cursor = rowptr + (N+1);             // N
  int*    bsum   = cursor + N;                 // 256
  int*    boff   = bsum + 256;                 // 256
  unsigned short* hb = (unsigned short*)(boff + 256);  // N*H bf16 shadow of h
  size_t needed = (size_t)((char*)(hb + NH) - (char*)d_ws);
  bool use_bf = (ws_size >= needed);

  hipMemsetAsync(deg, 0, sizeof(int)*(size_t)N, stream);
  hipMemsetAsync(stats, 0, sizeof(float)*768, stream);

  int gE = (E+255)/256;
  k_hist<<<gE,256,0,stream>>>(col,E,deg);
  int NB=(N+511)/512;
  k_scan1<<<NB,512,0,stream>>>(deg,N,bsum);
  k_scan2<<<1,256,0,stream>>>(bsum,NB,boff);
  k_scan3<<<NB,512,0,stream>>>(deg,N,E,boff,rowptr,cursor,dnorm);
  k_fill<<<gE,256,0,stream>>>(row,col,ew,E,dnorm,cursor,pairs);

  int GB=(N+31)/32;
  int gApply=((N*32)+255)/256;
  int gSpmm=(N+3)/4;
  float invN=1.f/(float)N;

  // stage 0: h = relu(bn(x @ fc_w + fc_b))
  k_gemm_bn<<<GB,256,0,stream>>>(x, fc_w, fc_b, zbuf, stats, N);
  k_bnfin<<<1,128,0,stream>>>(stats, gamma, beta, mi, invN);
  k_apply<<<gApply,256,0,stream>>>(zbuf, mi, nullptr, out, use_bf?hb:nullptr, N*32);

  // layers: z = relu(bn(agg(h) @ Wl + bl)); h = z + h
  for(int l=0;l<2;l++){
    if(use_bf)
      k_spmm_bf<<<gSpmm,256,0,stream>>>(pairs,rowptr,dnorm,hb,zbuf,N);
    else
      k_spmm<<<gSpmm,256,0,stream>>>(pairs,rowptr,dnorm,out,zbuf,N);
    k_gemm_bn<<<GB,256,0,stream>>>(zbuf, conv_w + (size_t)l*H*H, conv_b + (size_t)l*H,
                                   zbuf, stats+256*(l+1), N);
    k_bnfin<<<1,128,0,stream>>>(stats+256*(l+1), gamma+H*(l+1), beta+H*(l+1), mi+256*(l+1), invN);
    k_apply<<<gApply,256,0,stream>>>(zbuf, mi+256*(l+1), out, out,
                                     (use_bf && l==0)?hb:nullptr, N*32);
  }
}

// Round 4
// 586.631 us; speedup vs baseline: 18.9291x; 1.3729x over previous
//
#include <hip/hip_runtime.h>

#define H 128
#define EPS 1e-5f

typedef __attribute__((ext_vector_type(8))) short bf16x8;
typedef __attribute__((ext_vector_type(4))) float f32x4;

__device__ inline unsigned short f2bf(float f){
  unsigned int u=__float_as_uint(f);
  return (unsigned short)((u + 0x7FFFu + ((u>>16)&1u))>>16);
}
__device__ inline unsigned int pack_bf16(float a, float b){
  unsigned int ua=__float_as_uint(a), ub=__float_as_uint(b);
  ua = (ua + 0x7FFFu + ((ua>>16)&1u)) >> 16;
  ub = (ub + 0x7FFFu + ((ub>>16)&1u)) & 0xFFFF0000u;
  return ua | ub;
}

// ---------------- degree histogram ----------------
__global__ void k_hist(const int* __restrict__ col, int E, int* __restrict__ deg){
  int i = blockIdx.x*blockDim.x+threadIdx.x;
  if(i<E) atomicAdd(&deg[col[i]],1);
}

// ---------------- 3-kernel exclusive scan of deg -> rowptr ----------------
__global__ void k_scan1(const int* __restrict__ deg, int N, int* __restrict__ bsum){
  __shared__ int s[512];
  int t=threadIdx.x; int i=blockIdx.x*512+t;
  s[t]=(i<N)?deg[i]:0; __syncthreads();
  for(int off=256;off>0;off>>=1){ if(t<off) s[t]+=s[t+off]; __syncthreads(); }
  if(t==0) bsum[blockIdx.x]=s[0];
}

__global__ void k_scan2(const int* __restrict__ bsum, int NB, int* __restrict__ boff){
  __shared__ int s[256];
  int t=threadIdx.x;
  int v=(t<NB)?bsum[t]:0;
  s[t]=v; __syncthreads();
  for(int off=1;off<256;off<<=1){ int u=(t>=off)?s[t-off]:0; __syncthreads(); s[t]+=u; __syncthreads(); }
  if(t<NB) boff[t]=s[t]-v;   // exclusive block offsets
}

__global__ void k_scan3(const int* __restrict__ deg, int N, int E, const int* __restrict__ boff,
                        int* __restrict__ rowptr, int* __restrict__ cursor, float* __restrict__ dnorm){
  __shared__ int s[512];
  int t=threadIdx.x; int i=blockIdx.x*512+t;
  int v=(i<N)?deg[i]:0;
  s[t]=v; __syncthreads();
  for(int off=1;off<512;off<<=1){ int u=(t>=off)?s[t-off]:0; __syncthreads(); s[t]+=u; __syncthreads(); }
  if(i<N){
    int ex=boff[blockIdx.x]+s[t]-v;     // exclusive prefix
    rowptr[i]=ex; cursor[i]=ex;
    dnorm[i]= (v>0) ? rsqrtf((float)v) : 0.f;  // nan_to_num: deg==0 -> coefficient 0
    if(i==N-1) rowptr[N]=E;
  }
}

// ---------------- CSR fill: pairs[pos] = (row, ew*dnorm[row]) ----------------
__global__ void k_fill(const int* __restrict__ row, const int* __restrict__ col,
                       const float* __restrict__ ew, int E, const float* __restrict__ dnorm,
                       int* __restrict__ cursor, float2* __restrict__ pairs){
  int e=blockIdx.x*blockDim.x+threadIdx.x;
  if(e<E){
    int r=row[e], d=col[e];
    int pos=atomicAdd(&cursor[d],1);
    pairs[pos]=make_float2(__int_as_float(r), ew[e]*dnorm[r]);
  }
}

// ---------------- SpMM bf16: wave/dest, 2 cols/lane (1 dword gather), unroll x4 ----------------
// 4 independent row gathers in flight per wave; writes bf16 (GEMM input dtype).
__global__ __launch_bounds__(256) void k_spmm_bf(const float2* __restrict__ pairs,
    const int* __restrict__ rowptr, const float* __restrict__ dnorm,
    const unsigned short* __restrict__ hb, unsigned short* __restrict__ zb, int N){
  int wid=(blockIdx.x*256+threadIdx.x)>>6;
  int lane=threadIdx.x&63;
  if(wid>=N) return;
  int beg=rowptr[wid], end=rowptr[wid+1];
  float ax=0.f, ay=0.f;
  int p=beg;
  for(; p+4<=end; p+=4){
    float2 pr0=pairs[p+0], pr1=pairs[p+1], pr2=pairs[p+2], pr3=pairs[p+3];
    unsigned int u0=*(const unsigned int*)(hb + (((size_t)__float_as_int(pr0.x))<<7) + (lane<<1));
    unsigned int u1=*(const unsigned int*)(hb + (((size_t)__float_as_int(pr1.x))<<7) + (lane<<1));
    unsigned int u2=*(const unsigned int*)(hb + (((size_t)__float_as_int(pr2.x))<<7) + (lane<<1));
    unsigned int u3=*(const unsigned int*)(hb + (((size_t)__float_as_int(pr3.x))<<7) + (lane<<1));
    ax=fmaf(pr0.y,__uint_as_float(u0<<16),ax); ay=fmaf(pr0.y,__uint_as_float(u0&0xFFFF0000u),ay);
    ax=fmaf(pr1.y,__uint_as_float(u1<<16),ax); ay=fmaf(pr1.y,__uint_as_float(u1&0xFFFF0000u),ay);
    ax=fmaf(pr2.y,__uint_as_float(u2<<16),ax); ay=fmaf(pr2.y,__uint_as_float(u2&0xFFFF0000u),ay);
    ax=fmaf(pr3.y,__uint_as_float(u3<<16),ax); ay=fmaf(pr3.y,__uint_as_float(u3&0xFFFF0000u),ay);
  }
  for(; p<end; ++p){
    float2 pr=pairs[p];
    unsigned int u=*(const unsigned int*)(hb + (((size_t)__float_as_int(pr.x))<<7) + (lane<<1));
    ax=fmaf(pr.y,__uint_as_float(u<<16),ax); ay=fmaf(pr.y,__uint_as_float(u&0xFFFF0000u),ay);
  }
  float dn=dnorm[wid];
  *(unsigned int*)(zb + ((size_t)wid<<7) + (lane<<1)) = pack_bf16(ax*dn, ay*dn);
}

// ---------------- MFMA GEMM (N x 128 @ 128 x 128) + fused BN sum/sumsq ----------------
// v3: bf16 MFMA 16x16x32 (v2's vector path was LDS-throughput-bound: 2 b128 reads
// per 16 FMA -> 3x LDS vs VALU, VALUBusy 28%). Wave = 64 rows x 128 cols
// (4 row-tiles x 8 ntiles, K = 4x32). B-frag reused across 4 row-tiles: 32 LDS
// reads per 128 MFMA (384 LDS cyc < 614 MFMA cyc). W staged once/block into LDS
// transposed bf16, pitch 136 (uniform bank coverage). A-frags straight from
// global (16B/lane, L1-hit). In-place safe: each block reads only rows it writes,
// all A reads precede stores. Layouts: A m=lane&15,k=quad*8+j; C/D col=lane&15,
// row=quad*4+reg [m89/m120-verified].
template<bool F32A>
__global__ __launch_bounds__(256,2) void k_gemm_bn(const void* __restrict__ Ap,
    const float* __restrict__ W, const float* __restrict__ bias,
    unsigned short* __restrict__ Zb, float* __restrict__ stats, int N){
  __shared__ __align__(16) unsigned short sWT[128*136];   // 34816 B
  int t=threadIdx.x;

  // stage W: fp32 row-major [k][c] -> bf16 transposed sWT[c][k]
  for(int it=t; it<4096; it+=256){
    float4 v=((const float4*)W)[it];
    int lin=it*4; int k=lin>>7; int c0=lin&127;
    sWT[(c0+0)*136+k]=f2bf(v.x);
    sWT[(c0+1)*136+k]=f2bf(v.y);
    sWT[(c0+2)*136+k]=f2bf(v.z);
    sWT[(c0+3)*136+k]=f2bf(v.w);
  }
  __syncthreads();

  int w=t>>6, lane=t&63, n=lane&15, quad=lane>>4;
  int r0w = blockIdx.x*256 + w*64;

  f32x4 acc[8][4];
  #pragma unroll
  for(int nt=0;nt<8;nt++)
    #pragma unroll
    for(int rt=0;rt<4;rt++){ f32x4 z4={0.f,0.f,0.f,0.f}; acc[nt][rt]=z4; }

  #pragma unroll
  for(int ks=0; ks<4; ks++){
    int k0 = ks*32 + quad*8;
    bf16x8 a[4];
    #pragma unroll
    for(int rt=0;rt<4;rt++){
      int r = r0w + rt*16 + n;
      bf16x8 af={0,0,0,0,0,0,0,0};
      if(r<N){
        if(F32A){
          const float* Af=(const float*)Ap;
          float4 u0=*(const float4*)&Af[(size_t)r*128 + k0];
          float4 u1=*(const float4*)&Af[(size_t)r*128 + k0 + 4];
          af[0]=(short)f2bf(u0.x); af[1]=(short)f2bf(u0.y);
          af[2]=(short)f2bf(u0.z); af[3]=(short)f2bf(u0.w);
          af[4]=(short)f2bf(u1.x); af[5]=(short)f2bf(u1.y);
          af[6]=(short)f2bf(u1.z); af[7]=(short)f2bf(u1.w);
        }else{
          af = *(const bf16x8*)((const unsigned short*)Ap + (size_t)r*128 + k0);
        }
      }
      a[rt]=af;
    }
    #pragma unroll
    for(int nt=0;nt<8;nt++){
      bf16x8 b = *(const bf16x8*)&sWT[(nt*16+n)*136 + k0];
      #pragma unroll
      for(int rt=0;rt<4;rt++)
        acc[nt][rt]=__builtin_amdgcn_mfma_f32_16x16x32_bf16(a[rt], b, acc[nt][rt], 0,0,0);
    }
  }

  __syncthreads();                        // all waves done with sWT -> reuse for stats
  float* sS=(float*)sWT;                  // [16][132]
  float* sQ=sS + 16*132;                  // [16][132]  (total 16896 B <= 34816)
  #pragma unroll
  for(int nt=0;nt<8;nt++){
    int c=nt*16+n;
    float bc=bias[c];
    float s=0.f,q=0.f;
    #pragma unroll
    for(int rt=0;rt<4;rt++){
      #pragma unroll
      for(int i=0;i<4;i++){
        int r=r0w + rt*16 + quad*4 + i;
        if(r<N){
          float z=acc[nt][rt][i]+bc;
          Zb[(size_t)r*128+c]=f2bf(z);
          s+=z; q+=z*z;
        }
      }
    }
    sS[(w*4+quad)*132+c]=s;
    sQ[(w*4+quad)*132+c]=q;
  }
  __syncthreads();
  if(t<128){
    float s=0.f,q=0.f;
    #pragma unroll
    for(int g=0;g<16;g++){ s+=sS[g*132+t]; q+=sQ[g*132+t]; }
    atomicAdd(&stats[t],s); atomicAdd(&stats[128+t],q);
  }
}

// ---------------- finalize BN: per-channel scale/shift ----------------
__global__ void k_bnfin(const float* __restrict__ stats, const float* __restrict__ gamma,
                        const float* __restrict__ beta, float* __restrict__ mi, float invN){
  int c=threadIdx.x;                       // 128 threads
  float mean=stats[c]*invN;
  float var=stats[128+c]*invN - mean*mean;
  float inv=rsqrtf(var+EPS);
  float sc=inv*gamma[c];
  mi[c]=sc; mi[128+c]=beta[c]-mean*sc;
}

// ---------------- apply BN + ReLU (+ residual) (+ bf16 shadow write) ----------------
__global__ __launch_bounds__(256) void k_apply(const unsigned short* __restrict__ Zb,
    const float* __restrict__ mi, const float* __restrict__ res,
    float* __restrict__ out, unsigned short* __restrict__ hb, int n4){
  int i=blockIdx.x*256+threadIdx.x;
  if(i>=n4) return;
  int c=(i&31)*4;
  uint2 zu=((const uint2*)Zb)[i];
  float4 z;
  z.x=__uint_as_float(zu.x<<16); z.y=__uint_as_float(zu.x&0xFFFF0000u);
  z.z=__uint_as_float(zu.y<<16); z.w=__uint_as_float(zu.y&0xFFFF0000u);
  float4 sc=*(const float4*)&mi[c];
  float4 sh=*(const float4*)&mi[128+c];
  float4 o;
  o.x=fmaxf(fmaf(z.x,sc.x,sh.x),0.f);
  o.y=fmaxf(fmaf(z.y,sc.y,sh.y),0.f);
  o.z=fmaxf(fmaf(z.z,sc.z,sh.z),0.f);
  o.w=fmaxf(fmaf(z.w,sc.w,sh.w),0.f);
  if(res){
    float4 r=((const float4*)res)[i];
    o.x+=r.x; o.y+=r.y; o.z+=r.z; o.w+=r.w;
  }
  ((float4*)out)[i]=o;
  if(hb){
    uint2 pk; pk.x=pack_bf16(o.x,o.y); pk.y=pack_bf16(o.z,o.w);
    ((uint2*)hb)[i]=pk;
  }
}

extern "C" void kernel_launch(void* const* d_in, const int* in_sizes, int n_in,
                              void* d_out, int out_size, void* d_ws, size_t ws_size,
                              hipStream_t stream){
  const float* x      = (const float*)d_in[0];
  const int*   ei     = (const int*)  d_in[1];
  const float* ew     = (const float*)d_in[2];
  const float* fc_w   = (const float*)d_in[3];
  const float* fc_b   = (const float*)d_in[4];
  const float* conv_w = (const float*)d_in[5];
  const float* conv_b = (const float*)d_in[6];
  const float* gamma  = (const float*)d_in[7];
  const float* beta   = (const float*)d_in[8];
  float* out = (float*)d_out;

  int N = in_sizes[0]/H;
  int E = in_sizes[2];
  const int* row = ei;
  const int* col = ei + E;

  // workspace layout (~66 MB, all-bf16 feature buffers)
  size_t NH = (size_t)N*H;
  unsigned short* zb = (unsigned short*)d_ws;    // N*H bf16: SpMM out / GEMM in+out
  unsigned short* hb = zb + NH;                  // N*H bf16: h shadow for SpMM gathers
  float2* pairs  = (float2*)(hb + NH);           // E
  float*  stats  = (float*)(pairs + E);          // 3*256
  float*  mi     = stats + 768;                  // 3*256
  int*    deg    = (int*)(mi + 768);             // N
  float*  dnorm  = (float*)(deg + N);            // N
  int*    rowptr = (int*)(dnorm + N);            // N+1
  int*    cursor = rowptr + (N+1);               // N
  int*    bsum   = cursor + N;                   // 256
  int*    boff   = bsum + 256;                   // 256

  hipMemsetAsync(deg, 0, sizeof(int)*(size_t)N, stream);
  hipMemsetAsync(stats, 0, sizeof(float)*768, stream);

  int gE = (E+255)/256;
  k_hist<<<gE,256,0,stream>>>(col,E,deg);
  int NB=(N+511)/512;
  k_scan1<<<NB,512,0,stream>>>(deg,N,bsum);
  k_scan2<<<1,256,0,stream>>>(bsum,NB,boff);
  k_scan3<<<NB,512,0,stream>>>(deg,N,E,boff,rowptr,cursor,dnorm);
  k_fill<<<gE,256,0,stream>>>(row,col,ew,E,dnorm,cursor,pairs);

  int GB=(N+255)/256;
  int gApply=((N*32)+255)/256;
  int gSpmm=(N+3)/4;
  float invN=1.f/(float)N;

  // stage 0: h = relu(bn(x @ fc_w + fc_b))
  k_gemm_bn<true><<<GB,256,0,stream>>>(x, fc_w, fc_b, zb, stats, N);
  k_bnfin<<<1,128,0,stream>>>(stats, gamma, beta, mi, invN);
  k_apply<<<gApply,256,0,stream>>>(zb, mi, nullptr, out, hb, N*32);

  // layers: z = relu(bn(agg(h) @ Wl + bl)); h = z + h
  for(int l=0;l<2;l++){
    k_spmm_bf<<<gSpmm,256,0,stream>>>(pairs,rowptr,dnorm,hb,zb,N);
    k_gemm_bn<false><<<GB,256,0,stream>>>(zb, conv_w + (size_t)l*H*H, conv_b + (size_t)l*H,
                                          zb, stats+256*(l+1), N);
    k_bnfin<<<1,128,0,stream>>>(stats+256*(l+1), gamma+H*(l+1), beta+H*(l+1), mi+256*(l+1), invN);
    k_apply<<<gApply,256,0,stream>>>(zb, mi+256*(l+1), out, out, (l==0)?hb:nullptr, N*32);
  }
}

// Round 5
// 525.342 us; speedup vs baseline: 21.1375x; 1.1167x over previous
//
#include <hip/hip_runtime.h>

#define H 128
#define EPS 1e-5f
#define NPB 256      // nodes per bucket (pow2); bucket = node >> 8

typedef __attribute__((ext_vector_type(8))) short bf16x8;
typedef __attribute__((ext_vector_type(4))) float f32x4;

__device__ inline unsigned short f2bf(float f){
  unsigned int u=__float_as_uint(f);
  return (unsigned short)((u + 0x7FFFu + ((u>>16)&1u))>>16);
}
__device__ inline unsigned int pack_bf16(float a, float b){
  unsigned int ua=__float_as_uint(a), ub=__float_as_uint(b);
  ua = (ua + 0x7FFFu + ((ua>>16)&1u)) >> 16;
  ub = (ub + 0x7FFFu + ((ub>>16)&1u)) & 0xFFFF0000u;
  return ua | ub;
}

// ============ CSR build via 2-level bucket sort (v4) ============
// v3's k_fill was a full-random 8B scatter over 12.8MB: WRITE_SIZE = E*64B = 101MB
// (1 line per edge). Bucketing bounds every scatter: binning writes land in per-block
// runs (~10 edges contiguous); final placement scatters only inside a 32KB bucket
// window (L1/L2). Also derives deg/dnorm/rowptr per bucket in LDS, killing k_hist +
// 3 N-wide scan kernels.

// ---- bucket histogram (block-local LDS, then 1 atomic per bucket) ----
__global__ __launch_bounds__(256) void k_bcount(const int* __restrict__ col, int E,
                                                int* __restrict__ bcnt){
  __shared__ int h[512];
  int t=threadIdx.x;
  for(int i=t;i<512;i+=256) h[i]=0;
  __syncthreads();
  int e0=blockIdx.x*4096, e1=min(e0+4096,E);
  for(int e=e0+t;e<e1;e+=256) atomicAdd(&h[((unsigned)col[e])>>8],1);
  __syncthreads();
  for(int i=t;i<512;i+=256) if(h[i]) atomicAdd(&bcnt[i],h[i]);
}

// ---- exclusive scan of bucket counts (single block) ----
__global__ void k_bscan(const int* __restrict__ bcnt, int B, int E,
                        int* __restrict__ bbase, int* __restrict__ cursor){
  __shared__ int s[512];
  int t=threadIdx.x;
  int v=(t<B)?bcnt[t]:0;
  s[t]=v; __syncthreads();
  for(int off=1;off<512;off<<=1){ int u=(t>=off)?s[t-off]:0; __syncthreads(); s[t]+=u; __syncthreads(); }
  if(t<B){ bbase[t]=s[t]-v; cursor[t]=s[t]-v; }
  if(t==0) bbase[B]=E;
}

// ---- binning: stg[...] = (local<<24 | row, ew), grouped by bucket ----
__global__ __launch_bounds__(256) void k_bfill(const int* __restrict__ row, const int* __restrict__ col,
    const float* __restrict__ ew, int E, int* __restrict__ cursor, uint2* __restrict__ stg){
  __shared__ int h[512];
  __shared__ int ofs[512];
  int t=threadIdx.x;
  for(int i=t;i<512;i+=256) h[i]=0;
  __syncthreads();
  int e0=blockIdx.x*4096, e1=min(e0+4096,E);
  for(int e=e0+t;e<e1;e+=256) atomicAdd(&h[((unsigned)col[e])>>8],1);
  __syncthreads();
  for(int i=t;i<512;i+=256) ofs[i] = h[i] ? atomicAdd(&cursor[i],h[i]) : 0;
  __syncthreads();
  for(int i=t;i<512;i+=256) h[i]=0;
  __syncthreads();
  for(int e=e0+t;e<e1;e+=256){
    unsigned d=(unsigned)col[e];
    int b=d>>8;
    int lp=atomicAdd(&h[b],1);
    stg[ofs[b]+lp]=make_uint2(((d&255u)<<24)|(unsigned)row[e], __float_as_uint(ew[e]));
  }
}

// ---- per-bucket: degree -> dnorm + rowptr (LDS count + scan) ----
__global__ __launch_bounds__(256) void k_p2a(const uint2* __restrict__ stg, const int* __restrict__ bbase,
    int N, int E, float* __restrict__ dnorm, int* __restrict__ rowptr){
  __shared__ int cnt[256];
  __shared__ int pre[256];
  int b=blockIdx.x, t=threadIdx.x;
  cnt[t]=0; __syncthreads();
  int s0=bbase[b], s1=bbase[b+1];
  for(int p=s0+t;p<s1;p+=256) atomicAdd(&cnt[stg[p].x>>24],1);
  __syncthreads();
  int v=cnt[t];
  pre[t]=v; __syncthreads();
  for(int off=1;off<256;off<<=1){ int u=(t>=off)?pre[t-off]:0; __syncthreads(); pre[t]+=u; __syncthreads(); }
  int node=(b<<8)+t;
  if(node<N){
    dnorm[node]= v>0 ? rsqrtf((float)v) : 0.f;   // nan_to_num: deg==0 -> coefficient 0
    rowptr[node]=s0+pre[t]-v;
    if(node==N-1) rowptr[N]=E;
  }
}

// ---- per-bucket: place records -> pairs (scatter bounded to ~32KB window) ----
__global__ __launch_bounds__(256) void k_p2b(const uint2* __restrict__ stg, const int* __restrict__ bbase,
    int N, const int* __restrict__ rowptr, float2* __restrict__ pairs){
  __shared__ int cur[256];
  int b=blockIdx.x, t=threadIdx.x;
  int node=(b<<8)+t;
  cur[t]=(node<N)?rowptr[node]:0;
  __syncthreads();
  int s0=bbase[b], s1=bbase[b+1];
  for(int p=s0+t;p<s1;p+=256){
    uint2 rec=stg[p];
    int pos=atomicAdd(&cur[rec.x>>24],1);
    pairs[pos]=make_float2(__int_as_float((int)(rec.x&0xFFFFFFu)), __uint_as_float(rec.y));
  }
}

// ---------------- SpMM bf16: wave/dest, 2 cols/lane, 8 gathers in flight ----------------
// hb rows are pre-scaled by dnorm[row] (folded in k_apply), so the inner loop is pure
// (pair, gather, fma); dnorm[dest] applied at epilogue.
__global__ __launch_bounds__(256) void k_spmm_bf(const float2* __restrict__ pairs,
    const int* __restrict__ rowptr, const float* __restrict__ dnorm,
    const unsigned short* __restrict__ hb, unsigned short* __restrict__ zb, int N){
  int wid=(blockIdx.x*256+threadIdx.x)>>6;
  int lane=threadIdx.x&63;
  if(wid>=N) return;
  int beg=rowptr[wid], end=rowptr[wid+1];
  float ax=0.f, ay=0.f;
  int p=beg;
  for(; p+8<=end; p+=8){
    float2 pr[8]; unsigned int u[8];
    #pragma unroll
    for(int j=0;j<8;j++) pr[j]=pairs[p+j];
    #pragma unroll
    for(int j=0;j<8;j++)
      u[j]=*(const unsigned int*)(hb + (((size_t)__float_as_int(pr[j].x))<<7) + (lane<<1));
    #pragma unroll
    for(int j=0;j<8;j++){
      ax=fmaf(pr[j].y,__uint_as_float(u[j]<<16),ax);
      ay=fmaf(pr[j].y,__uint_as_float(u[j]&0xFFFF0000u),ay);
    }
  }
  for(; p<end; ++p){
    float2 pr=pairs[p];
    unsigned int u=*(const unsigned int*)(hb + (((size_t)__float_as_int(pr.x))<<7) + (lane<<1));
    ax=fmaf(pr.y,__uint_as_float(u<<16),ax); ay=fmaf(pr.y,__uint_as_float(u&0xFFFF0000u),ay);
  }
  float dn=dnorm[wid];
  *(unsigned int*)(zb + ((size_t)wid<<7) + (lane<<1)) = pack_bf16(ax*dn, ay*dn);
}

// ---------------- MFMA GEMM (N x 128 @ 128 x 128) + fused BN sum/sumsq ----------------
// bf16 MFMA 16x16x32. Wave = 64 rows x 128 cols (4 row-tiles x 8 ntiles, K = 4x32).
// W staged once/block into LDS transposed bf16 (pitch 136). A-frags straight from
// global (16B/lane). In-place safe. Layouts: A m=lane&15,k=quad*8+j; C/D col=lane&15,
// row=quad*4+reg [m89/m120-verified].
template<bool F32A>
__global__ __launch_bounds__(256,2) void k_gemm_bn(const void* __restrict__ Ap,
    const float* __restrict__ W, const float* __restrict__ bias,
    unsigned short* __restrict__ Zb, float* __restrict__ stats, int N){
  __shared__ __align__(16) unsigned short sWT[128*136];   // 34816 B
  int t=threadIdx.x;

  for(int it=t; it<4096; it+=256){
    float4 v=((const float4*)W)[it];
    int lin=it*4; int k=lin>>7; int c0=lin&127;
    sWT[(c0+0)*136+k]=f2bf(v.x);
    sWT[(c0+1)*136+k]=f2bf(v.y);
    sWT[(c0+2)*136+k]=f2bf(v.z);
    sWT[(c0+3)*136+k]=f2bf(v.w);
  }
  __syncthreads();

  int w=t>>6, lane=t&63, n=lane&15, quad=lane>>4;
  int r0w = blockIdx.x*256 + w*64;

  f32x4 acc[8][4];
  #pragma unroll
  for(int nt=0;nt<8;nt++)
    #pragma unroll
    for(int rt=0;rt<4;rt++){ f32x4 z4={0.f,0.f,0.f,0.f}; acc[nt][rt]=z4; }

  #pragma unroll
  for(int ks=0; ks<4; ks++){
    int k0 = ks*32 + quad*8;
    bf16x8 a[4];
    #pragma unroll
    for(int rt=0;rt<4;rt++){
      int r = r0w + rt*16 + n;
      bf16x8 af={0,0,0,0,0,0,0,0};
      if(r<N){
        if(F32A){
          const float* Af=(const float*)Ap;
          float4 u0=*(const float4*)&Af[(size_t)r*128 + k0];
          float4 u1=*(const float4*)&Af[(size_t)r*128 + k0 + 4];
          af[0]=(short)f2bf(u0.x); af[1]=(short)f2bf(u0.y);
          af[2]=(short)f2bf(u0.z); af[3]=(short)f2bf(u0.w);
          af[4]=(short)f2bf(u1.x); af[5]=(short)f2bf(u1.y);
          af[6]=(short)f2bf(u1.z); af[7]=(short)f2bf(u1.w);
        }else{
          af = *(const bf16x8*)((const unsigned short*)Ap + (size_t)r*128 + k0);
        }
      }
      a[rt]=af;
    }
    #pragma unroll
    for(int nt=0;nt<8;nt++){
      bf16x8 b = *(const bf16x8*)&sWT[(nt*16+n)*136 + k0];
      #pragma unroll
      for(int rt=0;rt<4;rt++)
        acc[nt][rt]=__builtin_amdgcn_mfma_f32_16x16x32_bf16(a[rt], b, acc[nt][rt], 0,0,0);
    }
  }

  __syncthreads();                        // reuse sWT for stats partials
  float* sS=(float*)sWT;                  // [16][132]
  float* sQ=sS + 16*132;                  // [16][132]
  #pragma unroll
  for(int nt=0;nt<8;nt++){
    int c=nt*16+n;
    float bc=bias[c];
    float s=0.f,q=0.f;
    #pragma unroll
    for(int rt=0;rt<4;rt++){
      #pragma unroll
      for(int i=0;i<4;i++){
        int r=r0w + rt*16 + quad*4 + i;
        if(r<N){
          float z=acc[nt][rt][i]+bc;
          Zb[(size_t)r*128+c]=f2bf(z);
          s+=z; q+=z*z;
        }
      }
    }
    sS[(w*4+quad)*132+c]=s;
    sQ[(w*4+quad)*132+c]=q;
  }
  __syncthreads();
  if(t<128){
    float s=0.f,q=0.f;
    #pragma unroll
    for(int g=0;g<16;g++){ s+=sS[g*132+t]; q+=sQ[g*132+t]; }
    atomicAdd(&stats[t],s); atomicAdd(&stats[128+t],q);
  }
}

// ---------------- finalize BN: per-channel scale/shift ----------------
__global__ void k_bnfin(const float* __restrict__ stats, const float* __restrict__ gamma,
                        const float* __restrict__ beta, float* __restrict__ mi, float invN){
  int c=threadIdx.x;                       // 128 threads
  float mean=stats[c]*invN;
  float var=stats[128+c]*invN - mean*mean;
  float inv=rsqrtf(var+EPS);
  float sc=inv*gamma[c];
  mi[c]=sc; mi[128+c]=beta[c]-mean*sc;
}

// ---------------- apply BN + ReLU (+ residual) (+ dnorm-scaled bf16 shadow) ----------------
__global__ __launch_bounds__(256) void k_apply(const unsigned short* __restrict__ Zb,
    const float* __restrict__ mi, const float* __restrict__ res,
    float* __restrict__ out, unsigned short* __restrict__ hb,
    const float* __restrict__ dnorm, int n4){
  int i=blockIdx.x*256+threadIdx.x;
  if(i>=n4) return;
  int c=(i&31)*4;
  uint2 zu=((const uint2*)Zb)[i];
  float4 z;
  z.x=__uint_as_float(zu.x<<16); z.y=__uint_as_float(zu.x&0xFFFF0000u);
  z.z=__uint_as_float(zu.y<<16); z.w=__uint_as_float(zu.y&0xFFFF0000u);
  float4 sc=*(const float4*)&mi[c];
  float4 sh=*(const float4*)&mi[128+c];
  float4 o;
  o.x=fmaxf(fmaf(z.x,sc.x,sh.x),0.f);
  o.y=fmaxf(fmaf(z.y,sc.y,sh.y),0.f);
  o.z=fmaxf(fmaf(z.z,sc.z,sh.z),0.f);
  o.w=fmaxf(fmaf(z.w,sc.w,sh.w),0.f);
  if(res){
    float4 r=((const float4*)res)[i];
    o.x+=r.x; o.y+=r.y; o.z+=r.z; o.w+=r.w;
  }
  ((float4*)out)[i]=o;
  if(hb){
    float dn=dnorm[i>>5];                  // fold dnorm[row] into gather operand
    uint2 pk; pk.x=pack_bf16(o.x*dn,o.y*dn); pk.y=pack_bf16(o.z*dn,o.w*dn);
    ((uint2*)hb)[i]=pk;
  }
}

extern "C" void kernel_launch(void* const* d_in, const int* in_sizes, int n_in,
                              void* d_out, int out_size, void* d_ws, size_t ws_size,
                              hipStream_t stream){
  const float* x      = (const float*)d_in[0];
  const int*   ei     = (const int*)  d_in[1];
  const float* ew     = (const float*)d_in[2];
  const float* fc_w   = (const float*)d_in[3];
  const float* fc_b   = (const float*)d_in[4];
  const float* conv_w = (const float*)d_in[5];
  const float* conv_b = (const float*)d_in[6];
  const float* gamma  = (const float*)d_in[7];
  const float* beta   = (const float*)d_in[8];
  float* out = (float*)d_out;

  int N = in_sizes[0]/H;
  int E = in_sizes[2];
  const int* row = ei;
  const int* col = ei + E;
  int B = (N+NPB-1)/NPB;                 // buckets (<=512 for N<=131072)

  // workspace layout (~78 MB)
  size_t NH = (size_t)N*H;
  unsigned short* zb = (unsigned short*)d_ws;    // N*H bf16: SpMM out / GEMM in+out
  unsigned short* hb = zb + NH;                  // N*H bf16: dnorm-scaled h shadow
  uint2*  stg    = (uint2*)(hb + NH);            // E bucket-grouped records
  float2* pairs  = (float2*)(stg + E);           // E final CSR records
  float*  stats  = (float*)(pairs + E);          // 3*256
  float*  mi     = stats + 768;                  // 3*256
  float*  dnorm  = mi + 768;                     // N
  int*    rowptr = (int*)(dnorm + N);            // N+1
  int*    bcnt   = rowptr + (N+1);               // 512
  int*    bbase  = bcnt + 512;                   // 513
  int*    cursor = bbase + 513;                  // 512

  hipMemsetAsync(bcnt, 0, sizeof(int)*512, stream);
  hipMemsetAsync(stats, 0, sizeof(float)*768, stream);

  int gE4k = (E+4095)/4096;
  k_bcount<<<gE4k,256,0,stream>>>(col,E,bcnt);
  k_bscan<<<1,512,0,stream>>>(bcnt,B,E,bbase,cursor);
  k_bfill<<<gE4k,256,0,stream>>>(row,col,ew,E,cursor,stg);
  k_p2a<<<B,256,0,stream>>>(stg,bbase,N,E,dnorm,rowptr);
  k_p2b<<<B,256,0,stream>>>(stg,bbase,N,rowptr,pairs);

  int GB=(N+255)/256;
  int gApply=((N*32)+255)/256;
  int gSpmm=(N+3)/4;
  float invN=1.f/(float)N;

  // stage 0: h = relu(bn(x @ fc_w + fc_b))
  k_gemm_bn<true><<<GB,256,0,stream>>>(x, fc_w, fc_b, zb, stats, N);
  k_bnfin<<<1,128,0,stream>>>(stats, gamma, beta, mi, invN);
  k_apply<<<gApply,256,0,stream>>>(zb, mi, nullptr, out, hb, dnorm, N*32);

  // layers: z = relu(bn(agg(h) @ Wl + bl)); h = z + h
  for(int l=0;l<2;l++){
    k_spmm_bf<<<gSpmm,256,0,stream>>>(pairs,rowptr,dnorm,hb,zb,N);
    k_gemm_bn<false><<<GB,256,0,stream>>>(zb, conv_w + (size_t)l*H*H, conv_b + (size_t)l*H,
                                          zb, stats+256*(l+1), N);
    k_bnfin<<<1,128,0,stream>>>(stats+256*(l+1), gamma+H*(l+1), beta+H*(l+1), mi+256*(l+1), invN);
    k_apply<<<gApply,256,0,stream>>>(zb, mi+256*(l+1), out, out, (l==0)?hb:nullptr, dnorm, N*32);
  }
}

// Round 6
// 506.440 us; speedup vs baseline: 21.9264x; 1.0373x over previous
//
#include <hip/hip_runtime.h>

#define H 128
#define EPS 1e-5f
#define NPB 256      // nodes per bucket (pow2); bucket = node >> 8

typedef __attribute__((ext_vector_type(8))) short bf16x8;
typedef __attribute__((ext_vector_type(4))) float f32x4;

__device__ inline unsigned short f2bf(float f){
  unsigned int u=__float_as_uint(f);
  return (unsigned short)((u + 0x7FFFu + ((u>>16)&1u))>>16);
}
__device__ inline unsigned int pack_bf16(float a, float b){
  unsigned int ua=__float_as_uint(a), ub=__float_as_uint(b);
  ua = (ua + 0x7FFFu + ((ua>>16)&1u)) >> 16;
  ub = (ub + 0x7FFFu + ((ub>>16)&1u)) & 0xFFFF0000u;
  return ua | ub;
}

// ============ CSR build via 2-level bucket sort ============
// Bucket = dest>>8. Binning writes land in per-block contiguous runs; final placement
// scatters only inside a ~32KB bucket window (L1/L2-resident). deg/dnorm/rowptr are
// derived per bucket in LDS. v5: k_p2b folds dnorm[row] into the edge value, so the
// SpMM gather source is UNSCALED h == the residual buffer (one bf16 buffer for both).

// ---- bucket histogram (block-local LDS, then 1 atomic per bucket) ----
__global__ __launch_bounds__(256) void k_bcount(const int* __restrict__ col, int E,
                                                int* __restrict__ bcnt){
  __shared__ int h[512];
  int t=threadIdx.x;
  for(int i=t;i<512;i+=256) h[i]=0;
  __syncthreads();
  int e0=blockIdx.x*4096, e1=min(e0+4096,E);
  for(int e=e0+t;e<e1;e+=256) atomicAdd(&h[((unsigned)col[e])>>8],1);
  __syncthreads();
  for(int i=t;i<512;i+=256) if(h[i]) atomicAdd(&bcnt[i],h[i]);
}

// ---- exclusive scan of bucket counts (single block) ----
__global__ void k_bscan(const int* __restrict__ bcnt, int B, int E,
                        int* __restrict__ bbase, int* __restrict__ cursor){
  __shared__ int s[512];
  int t=threadIdx.x;
  int v=(t<B)?bcnt[t]:0;
  s[t]=v; __syncthreads();
  for(int off=1;off<512;off<<=1){ int u=(t>=off)?s[t-off]:0; __syncthreads(); s[t]+=u; __syncthreads(); }
  if(t<B){ bbase[t]=s[t]-v; cursor[t]=s[t]-v; }
  if(t==0) bbase[B]=E;
}

// ---- binning: stg[...] = (local<<24 | row, ew), grouped by bucket ----
__global__ __launch_bounds__(256) void k_bfill(const int* __restrict__ row, const int* __restrict__ col,
    const float* __restrict__ ew, int E, int* __restrict__ cursor, uint2* __restrict__ stg){
  __shared__ int h[512];
  __shared__ int ofs[512];
  int t=threadIdx.x;
  for(int i=t;i<512;i+=256) h[i]=0;
  __syncthreads();
  int e0=blockIdx.x*4096, e1=min(e0+4096,E);
  for(int e=e0+t;e<e1;e+=256) atomicAdd(&h[((unsigned)col[e])>>8],1);
  __syncthreads();
  for(int i=t;i<512;i+=256) ofs[i] = h[i] ? atomicAdd(&cursor[i],h[i]) : 0;
  __syncthreads();
  for(int i=t;i<512;i+=256) h[i]=0;
  __syncthreads();
  for(int e=e0+t;e<e1;e+=256){
    unsigned d=(unsigned)col[e];
    int b=d>>8;
    int lp=atomicAdd(&h[b],1);
    stg[ofs[b]+lp]=make_uint2(((d&255u)<<24)|(unsigned)row[e], __float_as_uint(ew[e]));
  }
}

// ---- per-bucket: degree -> dnorm + rowptr (LDS count + scan) ----
__global__ __launch_bounds__(256) void k_p2a(const uint2* __restrict__ stg, const int* __restrict__ bbase,
    int N, int E, float* __restrict__ dnorm, int* __restrict__ rowptr){
  __shared__ int cnt[256];
  __shared__ int pre[256];
  int b=blockIdx.x, t=threadIdx.x;
  cnt[t]=0; __syncthreads();
  int s0=bbase[b], s1=bbase[b+1];
  for(int p=s0+t;p<s1;p+=256) atomicAdd(&cnt[stg[p].x>>24],1);
  __syncthreads();
  int v=cnt[t];
  pre[t]=v; __syncthreads();
  for(int off=1;off<256;off<<=1){ int u=(t>=off)?pre[t-off]:0; __syncthreads(); pre[t]+=u; __syncthreads(); }
  int node=(b<<8)+t;
  if(node<N){
    dnorm[node]= v>0 ? rsqrtf((float)v) : 0.f;   // nan_to_num: deg==0 -> coefficient 0
    rowptr[node]=s0+pre[t]-v;
    if(node==N-1) rowptr[N]=E;
  }
}

// ---- per-bucket: place records -> pairs, folding dnorm[row] into the value ----
// dnorm table is 400KB -> L2-resident, so the random dnorm[row] gather is cheap here.
__global__ __launch_bounds__(256) void k_p2b(const uint2* __restrict__ stg, const int* __restrict__ bbase,
    int N, const int* __restrict__ rowptr, const float* __restrict__ dnorm,
    float2* __restrict__ pairs){
  __shared__ int cur[256];
  int b=blockIdx.x, t=threadIdx.x;
  int node=(b<<8)+t;
  cur[t]=(node<N)?rowptr[node]:0;
  __syncthreads();
  int s0=bbase[b], s1=bbase[b+1];
  for(int p=s0+t;p<s1;p+=256){
    uint2 rec=stg[p];
    int r=(int)(rec.x&0xFFFFFFu);
    int pos=atomicAdd(&cur[rec.x>>24],1);
    pairs[pos]=make_float2(__int_as_float(r), __uint_as_float(rec.y)*dnorm[r]);
  }
}

// ---------------- SpMM bf16: wave/dest, 2 cols/lane, 16 gathers in flight ----------------
// pairs values carry ew*dnorm[row]; gather source is unscaled bf16 h (hbuf).
// dnorm[dest] applied at epilogue. MLP 16 covers the avg degree (16) in one batch.
__global__ __launch_bounds__(256) void k_spmm_bf(const float2* __restrict__ pairs,
    const int* __restrict__ rowptr, const float* __restrict__ dnorm,
    const unsigned short* __restrict__ hb, unsigned short* __restrict__ zb, int N){
  int wid=(blockIdx.x*256+threadIdx.x)>>6;
  int lane=threadIdx.x&63;
  if(wid>=N) return;
  int beg=rowptr[wid], end=rowptr[wid+1];
  float ax=0.f, ay=0.f;
  int p=beg;
  for(; p+16<=end; p+=16){
    float2 pr[16]; unsigned int u[16];
    #pragma unroll
    for(int j=0;j<16;j++) pr[j]=pairs[p+j];
    #pragma unroll
    for(int j=0;j<16;j++)
      u[j]=*(const unsigned int*)(hb + (((size_t)__float_as_int(pr[j].x))<<7) + (lane<<1));
    #pragma unroll
    for(int j=0;j<16;j++){
      ax=fmaf(pr[j].y,__uint_as_float(u[j]<<16),ax);
      ay=fmaf(pr[j].y,__uint_as_float(u[j]&0xFFFF0000u),ay);
    }
  }
  for(; p+4<=end; p+=4){
    float2 pr[4]; unsigned int u[4];
    #pragma unroll
    for(int j=0;j<4;j++) pr[j]=pairs[p+j];
    #pragma unroll
    for(int j=0;j<4;j++)
      u[j]=*(const unsigned int*)(hb + (((size_t)__float_as_int(pr[j].x))<<7) + (lane<<1));
    #pragma unroll
    for(int j=0;j<4;j++){
      ax=fmaf(pr[j].y,__uint_as_float(u[j]<<16),ax);
      ay=fmaf(pr[j].y,__uint_as_float(u[j]&0xFFFF0000u),ay);
    }
  }
  for(; p<end; ++p){
    float2 pr=pairs[p];
    unsigned int u=*(const unsigned int*)(hb + (((size_t)__float_as_int(pr.x))<<7) + (lane<<1));
    ax=fmaf(pr.y,__uint_as_float(u<<16),ax); ay=fmaf(pr.y,__uint_as_float(u&0xFFFF0000u),ay);
  }
  float dn=dnorm[wid];
  *(unsigned int*)(zb + ((size_t)wid<<7) + (lane<<1)) = pack_bf16(ax*dn, ay*dn);
}

// ---------------- MFMA GEMM (N x 128 @ 128 x 128) + fused BN sum/sumsq ----------------
// bf16 MFMA 16x16x32. Wave = 64 rows x 128 cols (4 row-tiles x 8 ntiles, K = 4x32).
// W staged once/block into LDS transposed bf16 (pitch 136). A-frags straight from
// global (16B/lane). In-place safe. Layouts: A m=lane&15,k=quad*8+j; C/D col=lane&15,
// row=quad*4+reg [m89/m120-verified].
template<bool F32A>
__global__ __launch_bounds__(256,2) void k_gemm_bn(const void* __restrict__ Ap,
    const float* __restrict__ W, const float* __restrict__ bias,
    unsigned short* __restrict__ Zb, float* __restrict__ stats, int N){
  __shared__ __align__(16) unsigned short sWT[128*136];   // 34816 B
  int t=threadIdx.x;

  for(int it=t; it<4096; it+=256){
    float4 v=((const float4*)W)[it];
    int lin=it*4; int k=lin>>7; int c0=lin&127;
    sWT[(c0+0)*136+k]=f2bf(v.x);
    sWT[(c0+1)*136+k]=f2bf(v.y);
    sWT[(c0+2)*136+k]=f2bf(v.z);
    sWT[(c0+3)*136+k]=f2bf(v.w);
  }
  __syncthreads();

  int w=t>>6, lane=t&63, n=lane&15, quad=lane>>4;
  int r0w = blockIdx.x*256 + w*64;

  f32x4 acc[8][4];
  #pragma unroll
  for(int nt=0;nt<8;nt++)
    #pragma unroll
    for(int rt=0;rt<4;rt++){ f32x4 z4={0.f,0.f,0.f,0.f}; acc[nt][rt]=z4; }

  #pragma unroll
  for(int ks=0; ks<4; ks++){
    int k0 = ks*32 + quad*8;
    bf16x8 a[4];
    #pragma unroll
    for(int rt=0;rt<4;rt++){
      int r = r0w + rt*16 + n;
      bf16x8 af={0,0,0,0,0,0,0,0};
      if(r<N){
        if(F32A){
          const float* Af=(const float*)Ap;
          float4 u0=*(const float4*)&Af[(size_t)r*128 + k0];
          float4 u1=*(const float4*)&Af[(size_t)r*128 + k0 + 4];
          af[0]=(short)f2bf(u0.x); af[1]=(short)f2bf(u0.y);
          af[2]=(short)f2bf(u0.z); af[3]=(short)f2bf(u0.w);
          af[4]=(short)f2bf(u1.x); af[5]=(short)f2bf(u1.y);
          af[6]=(short)f2bf(u1.z); af[7]=(short)f2bf(u1.w);
        }else{
          af = *(const bf16x8*)((const unsigned short*)Ap + (size_t)r*128 + k0);
        }
      }
      a[rt]=af;
    }
    #pragma unroll
    for(int nt=0;nt<8;nt++){
      bf16x8 b = *(const bf16x8*)&sWT[(nt*16+n)*136 + k0];
      #pragma unroll
      for(int rt=0;rt<4;rt++)
        acc[nt][rt]=__builtin_amdgcn_mfma_f32_16x16x32_bf16(a[rt], b, acc[nt][rt], 0,0,0);
    }
  }

  __syncthreads();                        // reuse sWT for stats partials
  float* sS=(float*)sWT;                  // [16][132]
  float* sQ=sS + 16*132;                  // [16][132]
  #pragma unroll
  for(int nt=0;nt<8;nt++){
    int c=nt*16+n;
    float bc=bias[c];
    float s=0.f,q=0.f;
    #pragma unroll
    for(int rt=0;rt<4;rt++){
      #pragma unroll
      for(int i=0;i<4;i++){
        int r=r0w + rt*16 + quad*4 + i;
        if(r<N){
          float z=acc[nt][rt][i]+bc;
          Zb[(size_t)r*128+c]=f2bf(z);
          s+=z; q+=z*z;
        }
      }
    }
    sS[(w*4+quad)*132+c]=s;
    sQ[(w*4+quad)*132+c]=q;
  }
  __syncthreads();
  if(t<128){
    float s=0.f,q=0.f;
    #pragma unroll
    for(int g=0;g<16;g++){ s+=sS[g*132+t]; q+=sQ[g*132+t]; }
    atomicAdd(&stats[t],s); atomicAdd(&stats[128+t],q);
  }
}

// ---------------- finalize BN: per-channel scale/shift ----------------
__global__ void k_bnfin(const float* __restrict__ stats, const float* __restrict__ gamma,
                        const float* __restrict__ beta, float* __restrict__ mi, float invN){
  int c=threadIdx.x;                       // 128 threads
  float mean=stats[c]*invN;
  float var=stats[128+c]*invN - mean*mean;
  float inv=rsqrtf(var+EPS);
  float sc=inv*gamma[c];
  mi[c]=sc; mi[128+c]=beta[c]-mean*sc;
}

// ---------------- apply BN + ReLU (+ bf16 residual) -> bf16 h OR final fp32 ----------------
// Intermediate h lives ONLY in bf16 (hbuf): gather source for SpMM and residual operand.
// Only the last layer writes the required fp32 d_out.
template<bool OUTF32>
__global__ __launch_bounds__(256) void k_apply(const unsigned short* __restrict__ Zb,
    const float* __restrict__ mi, const unsigned short* __restrict__ res,
    float* __restrict__ outf, unsigned short* __restrict__ outb, int n4){
  int i=blockIdx.x*256+threadIdx.x;
  if(i>=n4) return;
  int c=(i&31)*4;
  uint2 zu=((const uint2*)Zb)[i];
  float4 z;
  z.x=__uint_as_float(zu.x<<16); z.y=__uint_as_float(zu.x&0xFFFF0000u);
  z.z=__uint_as_float(zu.y<<16); z.w=__uint_as_float(zu.y&0xFFFF0000u);
  float4 sc=*(const float4*)&mi[c];
  float4 sh=*(const float4*)&mi[128+c];
  float4 o;
  o.x=fmaxf(fmaf(z.x,sc.x,sh.x),0.f);
  o.y=fmaxf(fmaf(z.y,sc.y,sh.y),0.f);
  o.z=fmaxf(fmaf(z.z,sc.z,sh.z),0.f);
  o.w=fmaxf(fmaf(z.w,sc.w,sh.w),0.f);
  if(res){
    uint2 ru=((const uint2*)res)[i];
    o.x+=__uint_as_float(ru.x<<16); o.y+=__uint_as_float(ru.x&0xFFFF0000u);
    o.z+=__uint_as_float(ru.y<<16); o.w+=__uint_as_float(ru.y&0xFFFF0000u);
  }
  if(OUTF32){
    ((float4*)outf)[i]=o;
  }else{
    uint2 pk; pk.x=pack_bf16(o.x,o.y); pk.y=pack_bf16(o.z,o.w);
    ((uint2*)outb)[i]=pk;
  }
}

extern "C" void kernel_launch(void* const* d_in, const int* in_sizes, int n_in,
                              void* d_out, int out_size, void* d_ws, size_t ws_size,
                              hipStream_t stream){
  const float* x      = (const float*)d_in[0];
  const int*   ei     = (const int*)  d_in[1];
  const float* ew     = (const float*)d_in[2];
  const float* fc_w   = (const float*)d_in[3];
  const float* fc_b   = (const float*)d_in[4];
  const float* conv_w = (const float*)d_in[5];
  const float* conv_b = (const float*)d_in[6];
  const float* gamma  = (const float*)d_in[7];
  const float* beta   = (const float*)d_in[8];
  float* out = (float*)d_out;

  int N = in_sizes[0]/H;
  int E = in_sizes[2];
  const int* row = ei;
  const int* col = ei + E;
  int B = (N+NPB-1)/NPB;                 // buckets

  // workspace layout (~78 MB)
  size_t NH = (size_t)N*H;
  unsigned short* zb   = (unsigned short*)d_ws;  // N*H bf16: SpMM out / GEMM in+out
  unsigned short* hbuf = zb + NH;                // N*H bf16: h (gather source + residual)
  uint2*  stg    = (uint2*)(hbuf + NH);          // E bucket-grouped records
  float2* pairs  = (float2*)(stg + E);           // E final CSR records (val = ew*dnorm[row])
  float*  stats  = (float*)(pairs + E);          // 3*256
  float*  mi     = stats + 768;                  // 3*256
  float*  dnorm  = mi + 768;                     // N
  int*    rowptr = (int*)(dnorm + N);            // N+1
  int*    bcnt   = rowptr + (N+1);               // 512
  int*    bbase  = bcnt + 512;                   // 513
  int*    cursor = bbase + 513;                  // 512

  hipMemsetAsync(bcnt, 0, sizeof(int)*512, stream);
  hipMemsetAsync(stats, 0, sizeof(float)*768, stream);

  int gE4k = (E+4095)/4096;
  k_bcount<<<gE4k,256,0,stream>>>(col,E,bcnt);
  k_bscan<<<1,512,0,stream>>>(bcnt,B,E,bbase,cursor);
  k_bfill<<<gE4k,256,0,stream>>>(row,col,ew,E,cursor,stg);
  k_p2a<<<B,256,0,stream>>>(stg,bbase,N,E,dnorm,rowptr);
  k_p2b<<<B,256,0,stream>>>(stg,bbase,N,rowptr,dnorm,pairs);

  int GB=(N+255)/256;
  int gApply=((N*32)+255)/256;
  int gSpmm=(N+3)/4;
  float invN=1.f/(float)N;

  // stage 0: h = relu(bn(x @ fc_w + fc_b))   [h kept in bf16 hbuf only]
  k_gemm_bn<true><<<GB,256,0,stream>>>(x, fc_w, fc_b, zb, stats, N);
  k_bnfin<<<1,128,0,stream>>>(stats, gamma, beta, mi, invN);
  k_apply<false><<<gApply,256,0,stream>>>(zb, mi, nullptr, nullptr, hbuf, N*32);

  // layer 0: h = relu(bn(agg(h) @ W0 + b0)) + h   -> bf16 hbuf
  k_spmm_bf<<<gSpmm,256,0,stream>>>(pairs,rowptr,dnorm,hbuf,zb,N);
  k_gemm_bn<false><<<GB,256,0,stream>>>(zb, conv_w, conv_b, zb, stats+256, N);
  k_bnfin<<<1,128,0,stream>>>(stats+256, gamma+H, beta+H, mi+256, invN);
  k_apply<false><<<gApply,256,0,stream>>>(zb, mi+256, hbuf, nullptr, hbuf, N*32);

  // layer 1: out = relu(bn(agg(h) @ W1 + b1)) + h  -> fp32 d_out (final)
  k_spmm_bf<<<gSpmm,256,0,stream>>>(pairs,rowptr,dnorm,hbuf,zb,N);
  k_gemm_bn<false><<<GB,256,0,stream>>>(zb, conv_w + (size_t)H*H, conv_b + H, zb, stats+512, N);
  k_bnfin<<<1,128,0,stream>>>(stats+512, gamma+2*H, beta+2*H, mi+512, invN);
  k_apply<true><<<gApply,256,0,stream>>>(zb, mi+512, hbuf, out, nullptr, N*32);
}